// Round 1
// baseline (348.798 us; speedup 1.0000x reference)
//
#include <hip/hip_runtime.h>

// Sinkhorn image loss, scaling-form (no log domain):
//   p = softmax(pred_logits)   per batch (N=2304)
//   q = target + 1e-8
//   K_ij = exp(-C_ij/eps) = exp(-100*C_ij)   (symmetric)
//   repeat 10x:  a = p / (K b) ;  b = q / (K a)
//   cost_b = sum_ij a_i b_j K_ij C_ij ;  out = mean_b cost_b
// Algebraically identical to the reference (u-cancellation + exp of duals);
// numerically safe in f32 since K_ii = 1 bounds every row-sum from below.

namespace {

constexpr int N  = 2304;          // 48*48
constexpr int B  = 16;
constexpr int NB = N * B;         // 36864
constexpr long long NN = (long long)N * N;  // 5,308,416

// ---------------------------------------------------------------- init ----
// One block per batch: softmax(pred) -> P, target+1e-8 -> Q, Bh = 1.
// Block 0 thread 0 zeroes d_out (final kernel accumulates via atomics).
__global__ __launch_bounds__(256) void sk_init(const float* __restrict__ logits,
                                               const float* __restrict__ target,
                                               float* __restrict__ P,
                                               float* __restrict__ Q,
                                               float* __restrict__ Bh,
                                               float* __restrict__ out) {
    const int b = blockIdx.x;
    const int t = threadIdx.x;

    float xs[9];
    float m = -3.0e38f;
#pragma unroll
    for (int s = 0; s < 9; ++s) {
        xs[s] = logits[b * N + s * 256 + t];
        m = fmaxf(m, xs[s]);
    }
#pragma unroll
    for (int off = 32; off >= 1; off >>= 1) m = fmaxf(m, __shfl_xor(m, off));

    __shared__ float sm[4], ss[4];
    const int w = t >> 6;
    if ((t & 63) == 0) sm[w] = m;
    __syncthreads();
    m = fmaxf(fmaxf(sm[0], sm[1]), fmaxf(sm[2], sm[3]));

    float sum = 0.f;
#pragma unroll
    for (int s = 0; s < 9; ++s) sum += __expf(xs[s] - m);
#pragma unroll
    for (int off = 32; off >= 1; off >>= 1) sum += __shfl_xor(sum, off);
    if ((t & 63) == 0) ss[w] = sum;
    __syncthreads();
    sum = ss[0] + ss[1] + ss[2] + ss[3];
    const float inv = 1.f / sum;

#pragma unroll
    for (int s = 0; s < 9; ++s) {
        const int i = s * 256 + t;
        P[b * N + i]  = __expf(xs[s] - m) * inv;
        Q[b * N + i]  = target[b * N + i] + 1e-8f;
        Bh[b * N + i] = 1.0f;
    }
    if (b == 0 && t == 0) out[0] = 0.f;
}

// ------------------------------------------------------------- K build ----
__global__ __launch_bounds__(256) void sk_mkK(const float* __restrict__ C,
                                              float* __restrict__ K) {
    const long long idx = ((long long)blockIdx.x * 256 + threadIdx.x) * 4;
    const float4 c4 = *(const float4*)(C + idx);
    float4 k4;
    k4.x = __expf(c4.x * -100.f);
    k4.y = __expf(c4.y * -100.f);
    k4.z = __expf(c4.z * -100.f);
    k4.w = __expf(c4.w * -100.f);
    *(float4*)(K + idx) = k4;
}

// ----------------------------------------------------------- half-iter ----
// out[b][i] = src[b][i] / sum_j K[i][j] * win[b][j]
// Grid 288 blocks x 256 thr. Block -> 8 rows; wave w -> batches 4w..4w+3,
// all 8 rows, full j range (64 lanes x float4 = 256 j per step, 9 steps).
template <bool USE_K>
__global__ __launch_bounds__(256) void sk_half(const float* __restrict__ C,
                                               const float* __restrict__ K,
                                               const float* __restrict__ src,
                                               const float* __restrict__ win,
                                               float* __restrict__ out) {
    const int i0    = blockIdx.x * 8;
    const int lane  = threadIdx.x & 63;
    const int bbase = (threadIdx.x >> 6) * 4;

    float acc[8][4];
#pragma unroll
    for (int r = 0; r < 8; ++r)
#pragma unroll
        for (int bb = 0; bb < 4; ++bb) acc[r][bb] = 0.f;

#pragma unroll
    for (int it = 0; it < 9; ++it) {
        const int j0 = (it * 64 + lane) * 4;
        float4 wv[4];
#pragma unroll
        for (int bb = 0; bb < 4; ++bb)
            wv[bb] = *(const float4*)(win + (bbase + bb) * N + j0);
#pragma unroll
        for (int r = 0; r < 8; ++r) {
            float4 k4;
            if (USE_K) {
                k4 = *(const float4*)(K + (long long)(i0 + r) * N + j0);
            } else {
                const float4 c4 = *(const float4*)(C + (long long)(i0 + r) * N + j0);
                k4.x = __expf(c4.x * -100.f);
                k4.y = __expf(c4.y * -100.f);
                k4.z = __expf(c4.z * -100.f);
                k4.w = __expf(c4.w * -100.f);
            }
#pragma unroll
            for (int bb = 0; bb < 4; ++bb) {
                acc[r][bb] = fmaf(k4.x, wv[bb].x, acc[r][bb]);
                acc[r][bb] = fmaf(k4.y, wv[bb].y, acc[r][bb]);
                acc[r][bb] = fmaf(k4.z, wv[bb].z, acc[r][bb]);
                acc[r][bb] = fmaf(k4.w, wv[bb].w, acc[r][bb]);
            }
        }
    }

    // wave all-reduce each of the 32 partial sums
#pragma unroll
    for (int r = 0; r < 8; ++r)
#pragma unroll
        for (int bb = 0; bb < 4; ++bb) {
#pragma unroll
            for (int off = 32; off >= 1; off >>= 1)
                acc[r][bb] += __shfl_xor(acc[r][bb], off);
        }

    // lanes 0..31 each own one (row, batch) output
#pragma unroll
    for (int r = 0; r < 8; ++r)
#pragma unroll
        for (int bb = 0; bb < 4; ++bb) {
            if (lane == r * 4 + bb) {
                const int gb = bbase + bb;
                const int gi = i0 + r;
                out[gb * N + gi] = src[gb * N + gi] / acc[r][bb];
            }
        }
}

// --------------------------------------------------------------- final ----
// partial = sum_{rows,b} A[b][i] * sum_j C[i][j]*K[i][j]*Bh[b][j]; atomicAdd.
__global__ __launch_bounds__(256) void sk_final(const float* __restrict__ C,
                                                const float* __restrict__ A,
                                                const float* __restrict__ Bh,
                                                float* __restrict__ out) {
    const int i0    = blockIdx.x * 8;
    const int lane  = threadIdx.x & 63;
    const int bbase = (threadIdx.x >> 6) * 4;

    float acc[8][4];
#pragma unroll
    for (int r = 0; r < 8; ++r)
#pragma unroll
        for (int bb = 0; bb < 4; ++bb) acc[r][bb] = 0.f;

#pragma unroll
    for (int it = 0; it < 9; ++it) {
        const int j0 = (it * 64 + lane) * 4;
        float4 wv[4];
#pragma unroll
        for (int bb = 0; bb < 4; ++bb)
            wv[bb] = *(const float4*)(Bh + (bbase + bb) * N + j0);
#pragma unroll
        for (int r = 0; r < 8; ++r) {
            const float4 c4 = *(const float4*)(C + (long long)(i0 + r) * N + j0);
            float4 kc;
            kc.x = __expf(c4.x * -100.f) * c4.x;
            kc.y = __expf(c4.y * -100.f) * c4.y;
            kc.z = __expf(c4.z * -100.f) * c4.z;
            kc.w = __expf(c4.w * -100.f) * c4.w;
#pragma unroll
            for (int bb = 0; bb < 4; ++bb) {
                acc[r][bb] = fmaf(kc.x, wv[bb].x, acc[r][bb]);
                acc[r][bb] = fmaf(kc.y, wv[bb].y, acc[r][bb]);
                acc[r][bb] = fmaf(kc.z, wv[bb].z, acc[r][bb]);
                acc[r][bb] = fmaf(kc.w, wv[bb].w, acc[r][bb]);
            }
        }
    }

#pragma unroll
    for (int r = 0; r < 8; ++r)
#pragma unroll
        for (int bb = 0; bb < 4; ++bb) {
#pragma unroll
            for (int off = 32; off >= 1; off >>= 1)
                acc[r][bb] += __shfl_xor(acc[r][bb], off);
        }

    // every lane now holds all 32 sums; dot with a-hat (broadcast loads)
    float val = 0.f;
#pragma unroll
    for (int r = 0; r < 8; ++r)
#pragma unroll
        for (int bb = 0; bb < 4; ++bb)
            val += A[(bbase + bb) * N + (i0 + r)] * acc[r][bb];

    if (lane == 0) atomicAdd(out, val * (1.f / 16.f));
}

}  // namespace

extern "C" void kernel_launch(void* const* d_in, const int* in_sizes, int n_in,
                              void* d_out, int out_size, void* d_ws, size_t ws_size,
                              hipStream_t stream) {
    const float* logits = (const float*)d_in[0];   // (B, 48, 48)
    const float* target = (const float*)d_in[1];   // (B, 48, 48)
    const float* C      = (const float*)d_in[2];   // (1, N, N)
    float* out = (float*)d_out;                    // scalar f32
    float* ws  = (float*)d_ws;

    float* Bh = ws;               // [B][N]
    float* A  = ws + NB;          // [B][N]
    float* P  = ws + 2 * NB;      // [B][N]
    float* Q  = ws + 3 * NB;      // [B][N]
    float* K  = ws + 4 * NB;      // [N][N] (optional)

    const size_t need_k = (size_t)(4 * NB) * 4 + (size_t)NN * 4;
    const bool use_k = ws_size >= need_k;

    sk_init<<<B, 256, 0, stream>>>(logits, target, P, Q, Bh, out);
    if (use_k) sk_mkK<<<(int)(NN / 1024), 256, 0, stream>>>(C, K);

    for (int t = 0; t < 10; ++t) {
        if (use_k) {
            sk_half<true><<<N / 8, 256, 0, stream>>>(C, K, P, Bh, A);
            sk_half<true><<<N / 8, 256, 0, stream>>>(C, K, Q, A, Bh);
        } else {
            sk_half<false><<<N / 8, 256, 0, stream>>>(C, K, P, Bh, A);
            sk_half<false><<<N / 8, 256, 0, stream>>>(C, K, Q, A, Bh);
        }
    }

    sk_final<<<N / 8, 256, 0, stream>>>(C, A, Bh, out);
}